// Round 10
// baseline (363.119 us; speedup 1.0000x reference)
//
#include <hip/hip_runtime.h>

// GCN scatter-aggregate, round 16 (= round 15 re-run; container infra failure).
// Key rule (r8 counters): scattered global writes interleaved across XCDs run
// at ~0.85 TB/s effective (cross-XCD partial-line RMW); block-private writes
// coalesce in the local L2. So k_part writes its sorted tile DENSELY to a
// private region + an (off,len) table; k_fine gathers runs per bucket.
//   k_pre   : Wf fragment conversion || zero deg/bsum + dummy h2 row
//   k_part  : per-tile bucket sort in LDS -> dense 4B-packed dump + offlen row
//             + global deg atomics + bsum (bucket totals)
//   k_scanb : scan bsum -> cbase
//   k_fine  : per bucket: gather 391 runs (prefix + binary search), fine sort
//             in LDS, emit rowptr/rend/dis + dense srcs
//   k_gemm  : h = bf16(rsqrt(deg) * (x @ W))  (MFMA)
//   k_aggr  : out[n] = dis[n] * sum(h[srcs[rowptr[n]..rend[n]]]) + bias
// Inputs: x fp32 [N,256], edge_index int32 [2,E] (row=dst, col=src),
//         W fp32 [256,128], bias fp32 [128]. Output fp32 [N,128].

#define N_FEAT 256
#define N_HID  128
#define D_BITS 8     // coarse bucket = dst >> 8 (256 dsts/bucket)
#define NBMAX 392    // ceil(100000/256) = 391
#define TILE 4096    // edges per k_part block
#define OSTRIDE 512  // offlen row stride (uints) per block
#define STCAP 4672   // k_fine stage capacity (bucket mean 4092, +9 sigma)

typedef float fx4    __attribute__((ext_vector_type(4)));
typedef float f32x16 __attribute__((ext_vector_type(16)));
typedef short bf16x8 __attribute__((ext_vector_type(8)));
typedef unsigned int u32x4 __attribute__((ext_vector_type(4)));

__device__ __forceinline__ float bf2f(unsigned int u) {
    return __uint_as_float(u << 16);
}
__device__ __forceinline__ float bf2f_hi(unsigned int u) {
    return __uint_as_float(u & 0xFFFF0000u);
}
__device__ __forceinline__ unsigned int f2bf(float f) {
    unsigned int u = __float_as_uint(f);
    return (u + 0x7FFFu + ((u >> 16) & 1u)) >> 16;  // round-nearest-even
}
__device__ __forceinline__ float deg2dis(int dg) {
    return (dg > 0) ? rsqrtf((float)dg) : 0.0f;
}

// ---- k_pre: Wf fragment conversion + deg/bsum/dummy-row zero ----------------
// Blocks 0..15: W -> fragment-ready bf16 (B-operand of mfma_f32_32x32x16_bf16).
// Frag f = kstep*4 + ntile; lane supplies B[k=kstep*16+(lane>>5)*8+j][n=ntile*32+(lane&31)].
// Block 16: zero bsum + dummy h2 row. All 64 blocks: grid-stride zero deg.
__global__ __launch_bounds__(256) void k_pre(const float* __restrict__ W,
                                             uint4* __restrict__ Wf,
                                             int* __restrict__ bsum,
                                             int* __restrict__ deg,
                                             unsigned int* __restrict__ h2d,
                                             int N) {
    const int b = blockIdx.x, t = threadIdx.x;
    if (b < 16) {
        int i = b * 256 + t;                  // 0..4095
        int lane = i & 63, f = i >> 6;
        int kstep = f >> 2, nt = f & 3;
        int n  = nt * 32 + (lane & 31);
        int kb = kstep * 16 + (lane >> 5) * 8;
        unsigned s[8];
#pragma unroll
        for (int j = 0; j < 8; ++j) s[j] = f2bf(W[(kb + j) * N_HID + n]);
        uint4 o;
        o.x = s[0] | (s[1] << 16);
        o.y = s[2] | (s[3] << 16);
        o.z = s[4] | (s[5] << 16);
        o.w = s[6] | (s[7] << 16);
        Wf[i] = o;
    } else if (b == 16) {
        bsum[t]       = 0;
        bsum[t + 256] = 0;
        if (t < 64) h2d[t] = 0;               // dummy zero row h2[N]
    }
    for (int i = b * 256 + t; i < N; i += 64 * 256) deg[i] = 0;
}

// ---- pass 1: per-tile bucket sort, DENSE block-private dump -----------------
// 1024 threads. Sorts the tile by coarse bucket in LDS (4B packed entries:
// (dst&255)<<17 | src), then streams it contiguously to pairs[blk*TILE ...]
// (block-private => no cross-XCD RMW). Emits offlen[blk][b] = (off<<13)|len,
// global deg atomics, and per-bucket totals bsum.
__global__ __launch_bounds__(1024) void k_part(const int* __restrict__ ei,
                                               unsigned int* __restrict__ pairs,
                                               unsigned int* __restrict__ offlen,
                                               int* __restrict__ bsum,
                                               int* __restrict__ deg,
                                               int E, int nb) {
    __shared__ int hist[NBMAX], cur[NBMAX];
    __shared__ int sc[512];
    __shared__ unsigned int sorted[TILE];   // 16 KB
    const int t  = threadIdx.x;
    const int blk = blockIdx.x;
    const int e0 = blk * TILE;
    const int cnt = min(TILE, E - e0);

    for (int b = t; b < nb; b += 1024) hist[b] = 0;
    __syncthreads();
    for (int i = t; i < cnt; i += 1024) {
        int d = ei[e0 + i];
        atomicAdd(&hist[d >> D_BITS], 1);
        atomicAdd(&deg[d], 1);              // device-scope, fire-and-forget
    }
    __syncthreads();

    // exclusive scan of per-bucket counts (512 slots; all-thread barriers)
    int v = 0;
    if (t < 512) {
        v = (t < nb) ? hist[t] : 0;
        sc[t] = v;
    }
    __syncthreads();
    for (int off = 1; off < 512; off <<= 1) {
        int a = 0;
        if (t < 512) { a = sc[t]; if (t >= off) a += sc[t - off]; }
        __syncthreads();
        if (t < 512) sc[t] = a;
        __syncthreads();
    }
    if (t < nb) {
        int ex = sc[t] - v;
        cur[t] = ex;
        // off 13 bits (<=4096), len 13 bits
        offlen[(size_t)blk * OSTRIDE + t] = ((unsigned)ex << 13) | (unsigned)v;
        if (v > 0) atomicAdd(&bsum[t], v);
    }
    __syncthreads();

    for (int i = t; i < cnt; i += 1024) {
        int d = ei[e0 + i];
        int s = ei[E + e0 + i];
        int b = d >> D_BITS;
        int p = atomicAdd(&cur[b], 1);
        sorted[p] = ((unsigned)(d & 255) << 17) | (unsigned)s;
    }
    __syncthreads();

    // dense, fully-coalesced, block-private dump
    for (int i = t; i < cnt; i += 1024)
        pairs[(size_t)blk * TILE + i] = sorted[i];
}

// ---- scan of bucket totals -> bucket bases ----------------------------------
__global__ __launch_bounds__(256) void k_scanb(const int* __restrict__ bsum,
                                               int* __restrict__ cbase,
                                               int nb) {
    __shared__ int sc[256];
    int t = threadIdx.x;
    int v0 = (2 * t     < nb) ? bsum[2 * t]     : 0;
    int v1 = (2 * t + 1 < nb) ? bsum[2 * t + 1] : 0;
    sc[t] = v0 + v1;
    __syncthreads();
    for (int off = 1; off < 256; off <<= 1) {
        int a = sc[t];
        int b = (t >= off) ? sc[t - off] : 0;
        __syncthreads();
        sc[t] = a + b;
        __syncthreads();
    }
    int ex = sc[t] - (v0 + v1);
    if (2 * t     < nb) cbase[2 * t]     = ex;
    if (2 * t + 1 < nb) cbase[2 * t + 1] = ex + v0;
}

// ---- pass 2: per-bucket gather + fine counting sort -------------------------
// Block = bucket b. Reads its (off,len) column (NBLK scattered 4B reads),
// prefix-scans run lengths, gathers all runs into LDS stage via binary
// search (load-balanced, coalesced within runs), then fine-sorts by dst&255:
// hist -> scan -> scatter to dense srcs segment. Emits rowptr/rend/dis.
__global__ __launch_bounds__(1024) void k_fine(const unsigned int* __restrict__ pairs,
                                               const unsigned int* __restrict__ offlen,
                                               const int* __restrict__ cbase,
                                               int* __restrict__ rowptr,
                                               int* __restrict__ rend,
                                               float* __restrict__ dis,
                                               int* __restrict__ srcs,
                                               int N, int nblk) {
    __shared__ int roff[NBMAX], rbase[NBMAX + 1];
    __shared__ int hist[256], cur[256], sc[512];
    __shared__ unsigned int stage[STCAP];   // 18.7 KB
    const int t = threadIdx.x;
    const int b = blockIdx.x;
    const int base = cbase[b];

    // load this bucket's (off,len) from every part-block; scan lengths
    int len = 0;
    if (t < 512) {
        if (t < nblk) {
            unsigned u = offlen[(size_t)t * OSTRIDE + b];
            roff[t] = (int)(u >> 13);
            len = (int)(u & 8191u);
        }
        sc[t] = len;
    }
    __syncthreads();
    for (int off = 1; off < 512; off <<= 1) {
        int a = 0;
        if (t < 512) { a = sc[t]; if (t >= off) a += sc[t - off]; }
        __syncthreads();
        if (t < 512) sc[t] = a;
        __syncthreads();
    }
    if (t < nblk) rbase[t] = sc[t] - len;   // exclusive
    if (t == 0) rbase[nblk] = sc[511];
    __syncthreads();
    const int R = rbase[nblk];              // total entries in bucket (<=STCAP)

    if (t < 256) hist[t] = 0;
    __syncthreads();

    // gather runs into stage (binary search for owning run)
    for (int i = t; i < R; i += 1024) {
        int lo = 0, hi = nblk - 1;
        while (lo < hi) {
            int mid = (lo + hi + 1) >> 1;
            if (rbase[mid] <= i) lo = mid; else hi = mid - 1;
        }
        unsigned e = pairs[(size_t)lo * TILE + roff[lo] + (i - rbase[lo])];
        stage[i] = e;
        atomicAdd(&hist[e >> 17], 1);
    }
    __syncthreads();

    int h = 0;
    if (t < 256) { h = hist[t]; sc[t] = h; }
    __syncthreads();
    for (int off = 1; off < 256; off <<= 1) {
        int a = 0;
        if (t < 256) { a = sc[t]; if (t >= off) a += sc[t - off]; }
        __syncthreads();
        if (t < 256) sc[t] = a;
        __syncthreads();
    }
    if (t < 256) {
        int ex = sc[t] - h;
        cur[t] = ex;
        int d = (b << D_BITS) + t;
        if (d < N) {
            rowptr[d] = base + ex;
            rend[d]   = base + ex + h;
            dis[d] = (h > 0) ? rsqrtf((float)h) : 0.0f;
        }
    }
    __syncthreads();

    // scatter to dense per-bucket srcs segment (block-private region)
    for (int i = t; i < R; i += 1024) {
        unsigned e = stage[i];
        int p = atomicAdd(&cur[e >> 17], 1);
        srcs[base + p] = (int)(e & 0x1FFFFu);
    }
}

// ---- h = bf16(rsqrt(deg) * (x @ W)) via MFMA, no LDS ------------------------
// Block = 4 waves; wave w covers rows mbase+w*32 .. +31, all 128 cols.
__global__ __launch_bounds__(256) void k_gemm(const float* __restrict__ x,
                                              const uint4* __restrict__ Wf,
                                              const int* __restrict__ deg,
                                              unsigned short* __restrict__ h2s,
                                              int N) {
    const int wave = threadIdx.x >> 6;
    const int lane = threadIdx.x & 63;
    const int half = lane >> 5;          // k sub-block 0/1 (8 elems each)
    const int lm   = lane & 31;
    const int mbase = blockIdx.x * 128 + wave * 32;
    const int arow  = min(mbase + lm, N - 1);   // clamp; garbage rows discarded

    const fx4* xr = (const fx4*)(x + (size_t)arow * N_FEAT) + half * 2;

    f32x16 acc0 = {0}, acc1 = {0}, acc2 = {0}, acc3 = {0};

#pragma unroll
    for (int ks = 0; ks < 16; ++ks) {
        fx4 a0 = xr[ks * 4];          // k = ks*16 + half*8 + (0..3)
        fx4 a1 = xr[ks * 4 + 1];      //                  + (4..7)
        union { bf16x8 v; unsigned u[4]; } A;
        A.u[0] = f2bf(a0.x) | (f2bf(a0.y) << 16);
        A.u[1] = f2bf(a0.z) | (f2bf(a0.w) << 16);
        A.u[2] = f2bf(a1.x) | (f2bf(a1.y) << 16);
        A.u[3] = f2bf(a1.z) | (f2bf(a1.w) << 16);
        union { bf16x8 v; uint4 q; } B0, B1, B2, B3;
        B0.q = Wf[(ks * 4 + 0) * 64 + lane];
        B1.q = Wf[(ks * 4 + 1) * 64 + lane];
        B2.q = Wf[(ks * 4 + 2) * 64 + lane];
        B3.q = Wf[(ks * 4 + 3) * 64 + lane];
        acc0 = __builtin_amdgcn_mfma_f32_32x32x16_bf16(A.v, B0.v, acc0, 0, 0, 0);
        acc1 = __builtin_amdgcn_mfma_f32_32x32x16_bf16(A.v, B1.v, acc1, 0, 0, 0);
        acc2 = __builtin_amdgcn_mfma_f32_32x32x16_bf16(A.v, B2.v, acc2, 0, 0, 0);
        acc3 = __builtin_amdgcn_mfma_f32_32x32x16_bf16(A.v, B3.v, acc3, 0, 0, 0);
    }

    // C/D: col = lane&31, row = (r&3) + 8*(r>>2) + 4*(lane>>5)   [m74/m101]
#pragma unroll
    for (int r = 0; r < 16; ++r) {
        int row  = (r & 3) + 8 * (r >> 2) + 4 * half;
        int node = mbase + row;
        if (node < N) {
            float dn = deg2dis(deg[node]);
            size_t o = (size_t)node * N_HID + lm;
            h2s[o +  0] = (unsigned short)f2bf(dn * acc0[r]);
            h2s[o + 32] = (unsigned short)f2bf(dn * acc1[r]);
            h2s[o + 64] = (unsigned short)f2bf(dn * acc2[r]);
            h2s[o + 96] = (unsigned short)f2bf(dn * acc3[r]);
        }
    }
}

// ---- aggregation: out[n] = dis[n] * sum(h[srcs]) + bias ---------------------
// One wave per node. 16-edge chunks: one coalesced srcs read, ds_bpermute
// distribution, 4x dwordx4 gathers (each covers 4 edge rows = 1 KB).
// Lane-group j = lane>>4 handles edge 4g+j of the chunk; lane q = lane&15
// holds hidden dims 8q..8q+7. Out-of-segment slots clamp to zero row h2[N].
__global__ __launch_bounds__(256) void k_aggr(const int* __restrict__ rowptr,
                                              const int* __restrict__ rend,
                                              const int* __restrict__ srcs,
                                              const u32x4* __restrict__ h2q,
                                              const float* __restrict__ dis,
                                              const float* __restrict__ bias,
                                              float4* __restrict__ out4, int N) {
    const int n    = blockIdx.x * 4 + (threadIdx.x >> 6);
    const int lane = threadIdx.x & 63;
    if (n >= N) return;
    const int j = lane >> 4;      // edge sub-slot within each gather
    const int q = lane & 15;      // 16B chunk (dims 8q..8q+7) within a row

    int i   = rowptr[n];
    int end = rend[n];
    float dn = dis[n];            // hoisted: overlaps with srcs/gather latency

    float a[8];
#pragma unroll
    for (int k = 0; k < 8; ++k) a[k] = 0.0f;

    for (; i < end; i += 16) {
        // one coalesced 64B read covers 16 src ids (srcs padded allocation)
        int cl = srcs[i + q];
#pragma unroll
        for (int g = 0; g < 4; ++g) {
            int cg  = __shfl(cl, 4 * g + j, 64);   // ds_bpermute
            int idx = i + 4 * g + j;
            cg = (idx < end) ? cg : N;             // dummy zero row for tail
            u32x4 v = h2q[(size_t)cg * 16 + q];    // dwordx4: 4 rows / instr
            a[0] += bf2f(v[0]);  a[1] += bf2f_hi(v[0]);
            a[2] += bf2f(v[1]);  a[3] += bf2f_hi(v[1]);
            a[4] += bf2f(v[2]);  a[5] += bf2f_hi(v[2]);
            a[6] += bf2f(v[3]);  a[7] += bf2f_hi(v[3]);
        }
    }

    // sum the 4 lane-groups (once per node)
#pragma unroll
    for (int k = 0; k < 8; ++k) {
        a[k] += __shfl_xor(a[k], 16, 64);
        a[k] += __shfl_xor(a[k], 32, 64);
    }

    if (lane < 16) {
        const float4* b4 = (const float4*)bias;
        float4 b0 = b4[q * 2], b1 = b4[q * 2 + 1];
        float4 o0, o1;
        o0.x = dn * a[0] + b0.x;  o0.y = dn * a[1] + b0.y;
        o0.z = dn * a[2] + b0.z;  o0.w = dn * a[3] + b0.w;
        o1.x = dn * a[4] + b1.x;  o1.y = dn * a[5] + b1.y;
        o1.z = dn * a[6] + b1.z;  o1.w = dn * a[7] + b1.w;
        out4[(size_t)n * 32 + q * 2]     = o0;
        out4[(size_t)n * 32 + q * 2 + 1] = o1;
    }
}

extern "C" void kernel_launch(void* const* d_in, const int* in_sizes, int n_in,
                              void* d_out, int out_size, void* d_ws, size_t ws_size,
                              hipStream_t stream) {
    const float* x    = (const float*)d_in[0];   // fp32 [N,256]
    const int*   ei   = (const int*)d_in[1];     // int32 [2,E]
    const float* W    = (const float*)d_in[2];   // fp32 [256,128]
    const float* bias = (const float*)d_in[3];   // fp32 [128]

    const int N = in_sizes[0] / N_FEAT;   // 100000
    const int E = in_sizes[1] / 2;        // 1600000
    const int nb   = (N + 255) >> D_BITS;       // 391 coarse buckets
    const int nblk = (E + TILE - 1) / TILE;     // 391 part blocks

    // workspace layout (~42 MB)
    char* ws = (char*)d_ws;
    size_t off = 0;
    int*          bsum   = (int*)(ws + off);   off += 512 * 4;
    int*          cbase  = (int*)(ws + off);   off += 512 * 4;
    int*          deg    = (int*)(ws + off);   off += (size_t)N * 4;
    int*          rowptr = (int*)(ws + off);   off += (size_t)(N + 4) * 4;
    int*          rend   = (int*)(ws + off);   off += (size_t)(N + 4) * 4;
    float*        dis    = (float*)(ws + off); off += (size_t)N * 4;
    int*          srcs   = (int*)(ws + off);   off += (size_t)E * 4 + 64;
    uint4*        Wf     = (uint4*)(ws + off); off += 4096 * 16;   // 64 KB
    unsigned int* offlen = (unsigned int*)(ws + off); off += (size_t)nblk * OSTRIDE * 4;
    unsigned int* pairs  = (unsigned int*)(ws + off); off += (size_t)nblk * TILE * 4;
    unsigned int* h2     = (unsigned int*)(ws + off);  // (N+1)*64 dwords

    k_pre<<<64, 256, 0, stream>>>(W, (uint4*)Wf, bsum, deg,
                                  h2 + (size_t)N * 64, N);
    k_part<<<nblk, 1024, 0, stream>>>(ei, pairs, offlen, bsum, deg, E, nb);
    k_scanb<<<1, 256, 0, stream>>>(bsum, cbase, nb);
    k_fine<<<nb, 1024, 0, stream>>>(pairs, offlen, cbase, rowptr, rend, dis,
                                    srcs, N, nblk);
    k_gemm<<<(N + 127) / 128, 256, 0, stream>>>(x, Wf, deg,
                                                (unsigned short*)h2, N);
    k_aggr<<<(N + 3) / 4, 256, 0, stream>>>(rowptr, rend, srcs, (const u32x4*)h2,
                                            dis, bias, (float4*)d_out, N);
}

// Round 11
// 310.341 us; speedup vs baseline: 1.1701x; 1.1701x over previous
//
#include <hip/hip_runtime.h>

// GCN scatter-aggregate, round 17: XCD-private bucket copies.
// Mechanism (r8/r10 counters): per-XCD L2s are private; a line written by
// blocks on multiple XCDs becomes partial dirty copies in several L2s ->
// partial-line RMW writeback at ~0.85 TB/s (r8 k_part: 67 MB WRITE = 79 us).
// Writes confined to one XCD's blocks coalesce in its L2 and write back dense.
//   k_pre   : Wf fragment conversion || zero gcur + dummy h2 row
//   k_part  : hist -> reserve -> scatter 4B-packed entries into copy blk&7
//             of pairs[8][nb][CCAP] (XCD-private, L2-coalesced writes)
//   k_scanb : sum 8 copies per bucket, scan -> cbase
//   k_fine  : per bucket: gather 8 coalesced runs into LDS, fine counting
//             sort, emit rowptr/rend/dis + dense srcs
//   k_gemm  : h = bf16(dis * (x @ W))  (MFMA)
//   k_aggr  : out[n] = dis[n]*sum(h[srcs])+bias -- split into 2 half-node
//             dispatches (~40 us each) so top-5 exposes the build kernels.
// Inputs: x fp32 [N,256], edge_index int32 [2,E] (row=dst, col=src),
//         W fp32 [256,128], bias fp32 [128]. Output fp32 [N,128].

#define N_FEAT 256
#define N_HID  128
#define D_BITS 8     // coarse bucket = dst >> 8 (256 dsts/bucket)
#define NBMAX 392    // ceil(100000/256) = 391
#define NCOPY 8      // XCD-private copies
#define CCAP 768     // per-(copy,bucket) capacity (mean 513, +11 sigma)
#define TILE 4096    // edges per k_part block
#define STCAP 4672   // k_fine stage capacity (bucket mean 4092, +9 sigma)

typedef float fx4    __attribute__((ext_vector_type(4)));
typedef float f32x16 __attribute__((ext_vector_type(16)));
typedef short bf16x8 __attribute__((ext_vector_type(8)));
typedef unsigned int u32x4 __attribute__((ext_vector_type(4)));

__device__ __forceinline__ float bf2f(unsigned int u) {
    return __uint_as_float(u << 16);
}
__device__ __forceinline__ float bf2f_hi(unsigned int u) {
    return __uint_as_float(u & 0xFFFF0000u);
}
__device__ __forceinline__ unsigned int f2bf(float f) {
    unsigned int u = __float_as_uint(f);
    return (u + 0x7FFFu + ((u >> 16) & 1u)) >> 16;  // round-nearest-even
}

// ---- k_pre: Wf fragment conversion + gcur/dummy-row zero --------------------
// Blocks 0..15: W -> fragment-ready bf16 (B-operand of mfma_f32_32x32x16_bf16).
// Frag f = kstep*4 + ntile; lane supplies B[k=kstep*16+(lane>>5)*8+j][n=ntile*32+(lane&31)].
// Block 16: zero gcur (8x512 ints) + dummy h2 row (clamp target of k_aggr).
__global__ __launch_bounds__(256) void k_pre(const float* __restrict__ W,
                                             uint4* __restrict__ Wf,
                                             int* __restrict__ gcur,
                                             unsigned int* __restrict__ h2d) {
    const int b = blockIdx.x, t = threadIdx.x;
    if (b < 16) {
        int i = b * 256 + t;                  // 0..4095
        int lane = i & 63, f = i >> 6;
        int kstep = f >> 2, nt = f & 3;
        int n  = nt * 32 + (lane & 31);
        int kb = kstep * 16 + (lane >> 5) * 8;
        unsigned s[8];
#pragma unroll
        for (int j = 0; j < 8; ++j) s[j] = f2bf(W[(kb + j) * N_HID + n]);
        uint4 o;
        o.x = s[0] | (s[1] << 16);
        o.y = s[2] | (s[3] << 16);
        o.z = s[4] | (s[5] << 16);
        o.w = s[6] | (s[7] << 16);
        Wf[i] = o;
    } else {
#pragma unroll
        for (int k = 0; k < 16; ++k) gcur[k * 256 + t] = 0;   // 8*512 ints
        if (t < 64) h2d[t] = 0;               // dummy zero row h2[N]
    }
}

// ---- pass 1: hist -> reserve -> scatter into XCD-private copy ---------------
// 1024 threads. No LDS staging, no scan: cur[b] starts at the globally
// reserved base, so the LDS-atomic rank IS the global slot. Writes are 4B
// scattered but confined to copy blk&7 (~1.2 MB, L2-resident) -> coalesce.
__global__ __launch_bounds__(1024) void k_part(const int* __restrict__ ei,
                                               unsigned int* __restrict__ pairs4,
                                               int* __restrict__ gcur,
                                               int E, int nb) {
    __shared__ int hist[NBMAX], cur[NBMAX];
    const int t = threadIdx.x;
    const int blk = blockIdx.x;
    const int cpy = blk & (NCOPY - 1);
    const int e0 = blk * TILE;
    const int cnt = min(TILE, E - e0);

    for (int b = t; b < nb; b += 1024) hist[b] = 0;
    __syncthreads();
    for (int i = t; i < cnt; i += 1024)
        atomicAdd(&hist[ei[e0 + i] >> D_BITS], 1);
    __syncthreads();
    for (int b = t; b < nb; b += 1024) {
        int v = hist[b];
        cur[b] = (v > 0) ? atomicAdd(&gcur[cpy * 512 + b], v) : 0;
    }
    __syncthreads();
    for (int i = t; i < cnt; i += 1024) {
        int d = ei[e0 + i];
        int s = ei[E + e0 + i];
        int b = d >> D_BITS;
        int p = atomicAdd(&cur[b], 1);
        pairs4[((size_t)cpy * NBMAX + b) * CCAP + p] =
            ((unsigned)(d & 255) << 17) | (unsigned)s;
    }
}

// ---- scan of bucket totals (summed over copies) -> bucket bases -------------
__global__ __launch_bounds__(256) void k_scanb(const int* __restrict__ gcur,
                                               int* __restrict__ cbase,
                                               int nb) {
    __shared__ int sc[256];
    int t = threadIdx.x;
    int v0 = 0, v1 = 0;
#pragma unroll
    for (int c = 0; c < NCOPY; ++c) {
        if (2 * t     < nb) v0 += gcur[c * 512 + 2 * t];
        if (2 * t + 1 < nb) v1 += gcur[c * 512 + 2 * t + 1];
    }
    sc[t] = v0 + v1;
    __syncthreads();
    for (int off = 1; off < 256; off <<= 1) {
        int a = sc[t];
        int b = (t >= off) ? sc[t - off] : 0;
        __syncthreads();
        sc[t] = a + b;
        __syncthreads();
    }
    int ex = sc[t] - (v0 + v1);
    if (2 * t     < nb) cbase[2 * t]     = ex;
    if (2 * t + 1 < nb) cbase[2 * t + 1] = ex + v0;
}

// ---- pass 2: gather 8 coalesced runs + fine counting sort -------------------
// Block = bucket b. The bucket's entries live in 8 contiguous runs (one per
// copy); a linear 8-way offset lookup replaces r10's 9-step binary search.
// Then hist -> scan -> scatter to the dense srcs segment (block-private).
__global__ __launch_bounds__(1024) void k_fine(const unsigned int* __restrict__ pairs4,
                                               const int* __restrict__ gcur,
                                               const int* __restrict__ cbase,
                                               int* __restrict__ rowptr,
                                               int* __restrict__ rend,
                                               float* __restrict__ dis,
                                               int* __restrict__ srcs,
                                               int N) {
    __shared__ int offs[NCOPY + 1];
    __shared__ int hist[256], cur[256], sc[256];
    __shared__ unsigned int stage[STCAP];   // 18.7 KB
    const int t = threadIdx.x;
    const int b = blockIdx.x;
    const int base = cbase[b];

    if (t == 0) {
        int acc = 0;
#pragma unroll
        for (int c = 0; c < NCOPY; ++c) { offs[c] = acc; acc += gcur[c * 512 + b]; }
        offs[NCOPY] = acc;
    }
    if (t < 256) hist[t] = 0;
    __syncthreads();
    const int R = offs[NCOPY];

    for (int i = t; i < R; i += 1024) {
        int c = 0;
        while (c < NCOPY - 1 && i >= offs[c + 1]) ++c;
        unsigned e = pairs4[((size_t)c * NBMAX + b) * CCAP + (i - offs[c])];
        stage[i] = e;
        atomicAdd(&hist[e >> 17], 1);
    }
    __syncthreads();

    int h = 0;
    if (t < 256) { h = hist[t]; sc[t] = h; }
    __syncthreads();
    for (int off = 1; off < 256; off <<= 1) {
        int a = 0;
        if (t < 256) { a = sc[t]; if (t >= off) a += sc[t - off]; }
        __syncthreads();
        if (t < 256) sc[t] = a;
        __syncthreads();
    }
    if (t < 256) {
        int ex = sc[t] - h;
        cur[t] = ex;
        int d = (b << D_BITS) + t;
        if (d < N) {
            rowptr[d] = base + ex;
            rend[d]   = base + ex + h;
            dis[d] = (h > 0) ? rsqrtf((float)h) : 0.0f;
        }
    }
    __syncthreads();

    for (int i = t; i < R; i += 1024) {
        unsigned e = stage[i];
        int p = atomicAdd(&cur[e >> 17], 1);
        srcs[base + p] = (int)(e & 0x1FFFFu);
    }
}

// ---- h = bf16(dis * (x @ W)) via MFMA, no LDS -------------------------------
// Block = 4 waves; wave w covers rows mbase+w*32 .. +31, all 128 cols.
__global__ __launch_bounds__(256) void k_gemm(const float* __restrict__ x,
                                              const uint4* __restrict__ Wf,
                                              const float* __restrict__ dis,
                                              unsigned short* __restrict__ h2s,
                                              int N) {
    const int wave = threadIdx.x >> 6;
    const int lane = threadIdx.x & 63;
    const int half = lane >> 5;          // k sub-block 0/1 (8 elems each)
    const int lm   = lane & 31;
    const int mbase = blockIdx.x * 128 + wave * 32;
    const int arow  = min(mbase + lm, N - 1);   // clamp; garbage rows discarded

    const fx4* xr = (const fx4*)(x + (size_t)arow * N_FEAT) + half * 2;

    f32x16 acc0 = {0}, acc1 = {0}, acc2 = {0}, acc3 = {0};

#pragma unroll
    for (int ks = 0; ks < 16; ++ks) {
        fx4 a0 = xr[ks * 4];          // k = ks*16 + half*8 + (0..3)
        fx4 a1 = xr[ks * 4 + 1];      //                  + (4..7)
        union { bf16x8 v; unsigned u[4]; } A;
        A.u[0] = f2bf(a0.x) | (f2bf(a0.y) << 16);
        A.u[1] = f2bf(a0.z) | (f2bf(a0.w) << 16);
        A.u[2] = f2bf(a1.x) | (f2bf(a1.y) << 16);
        A.u[3] = f2bf(a1.z) | (f2bf(a1.w) << 16);
        union { bf16x8 v; uint4 q; } B0, B1, B2, B3;
        B0.q = Wf[(ks * 4 + 0) * 64 + lane];
        B1.q = Wf[(ks * 4 + 1) * 64 + lane];
        B2.q = Wf[(ks * 4 + 2) * 64 + lane];
        B3.q = Wf[(ks * 4 + 3) * 64 + lane];
        acc0 = __builtin_amdgcn_mfma_f32_32x32x16_bf16(A.v, B0.v, acc0, 0, 0, 0);
        acc1 = __builtin_amdgcn_mfma_f32_32x32x16_bf16(A.v, B1.v, acc1, 0, 0, 0);
        acc2 = __builtin_amdgcn_mfma_f32_32x32x16_bf16(A.v, B2.v, acc2, 0, 0, 0);
        acc3 = __builtin_amdgcn_mfma_f32_32x32x16_bf16(A.v, B3.v, acc3, 0, 0, 0);
    }

    // C/D: col = lane&31, row = (r&3) + 8*(r>>2) + 4*(lane>>5)   [m74/m101]
#pragma unroll
    for (int r = 0; r < 16; ++r) {
        int row  = (r & 3) + 8 * (r >> 2) + 4 * half;
        int node = mbase + row;
        if (node < N) {
            float dn = dis[node];
            size_t o = (size_t)node * N_HID + lm;
            h2s[o +  0] = (unsigned short)f2bf(dn * acc0[r]);
            h2s[o + 32] = (unsigned short)f2bf(dn * acc1[r]);
            h2s[o + 64] = (unsigned short)f2bf(dn * acc2[r]);
            h2s[o + 96] = (unsigned short)f2bf(dn * acc3[r]);
        }
    }
}

// ---- aggregation: out[n] = dis[n] * sum(h[srcs]) + bias ---------------------
// One wave per node, nodes [n0, nEnd). 16-edge chunks: one coalesced srcs
// read, ds_bpermute distribution, 4x dwordx4 gathers (4 edge rows = 1 KB).
// Lane-group j = lane>>4 handles edge 4g+j; lane q = lane&15 holds dims
// 8q..8q+7. Out-of-segment slots clamp to zero row h2[N].
__global__ __launch_bounds__(256) void k_aggr(const int* __restrict__ rowptr,
                                              const int* __restrict__ rend,
                                              const int* __restrict__ srcs,
                                              const u32x4* __restrict__ h2q,
                                              const float* __restrict__ dis,
                                              const float* __restrict__ bias,
                                              float4* __restrict__ out4,
                                              int n0, int nEnd, int N) {
    const int n    = n0 + blockIdx.x * 4 + (threadIdx.x >> 6);
    const int lane = threadIdx.x & 63;
    if (n >= nEnd) return;
    const int j = lane >> 4;      // edge sub-slot within each gather
    const int q = lane & 15;      // 16B chunk (dims 8q..8q+7) within a row

    int i   = rowptr[n];
    int end = rend[n];
    float dn = dis[n];            // hoisted: overlaps with srcs/gather latency

    float a[8];
#pragma unroll
    for (int k = 0; k < 8; ++k) a[k] = 0.0f;

    for (; i < end; i += 16) {
        // one coalesced 64B read covers 16 src ids (srcs padded allocation)
        int cl = srcs[i + q];
#pragma unroll
        for (int g = 0; g < 4; ++g) {
            int cg  = __shfl(cl, 4 * g + j, 64);   // ds_bpermute
            int idx = i + 4 * g + j;
            cg = (idx < end) ? cg : N;             // dummy zero row for tail
            u32x4 v = h2q[(size_t)cg * 16 + q];    // dwordx4: 4 rows / instr
            a[0] += bf2f(v[0]);  a[1] += bf2f_hi(v[0]);
            a[2] += bf2f(v[1]);  a[3] += bf2f_hi(v[1]);
            a[4] += bf2f(v[2]);  a[5] += bf2f_hi(v[2]);
            a[6] += bf2f(v[3]);  a[7] += bf2f_hi(v[3]);
        }
    }

    // sum the 4 lane-groups (once per node)
#pragma unroll
    for (int k = 0; k < 8; ++k) {
        a[k] += __shfl_xor(a[k], 16, 64);
        a[k] += __shfl_xor(a[k], 32, 64);
    }

    if (lane < 16) {
        const float4* b4 = (const float4*)bias;
        float4 b0 = b4[q * 2], b1 = b4[q * 2 + 1];
        float4 o0, o1;
        o0.x = dn * a[0] + b0.x;  o0.y = dn * a[1] + b0.y;
        o0.z = dn * a[2] + b0.z;  o0.w = dn * a[3] + b0.w;
        o1.x = dn * a[4] + b1.x;  o1.y = dn * a[5] + b1.y;
        o1.z = dn * a[6] + b1.z;  o1.w = dn * a[7] + b1.w;
        out4[(size_t)n * 32 + q * 2]     = o0;
        out4[(size_t)n * 32 + q * 2 + 1] = o1;
    }
}

extern "C" void kernel_launch(void* const* d_in, const int* in_sizes, int n_in,
                              void* d_out, int out_size, void* d_ws, size_t ws_size,
                              hipStream_t stream) {
    const float* x    = (const float*)d_in[0];   // fp32 [N,256]
    const int*   ei   = (const int*)d_in[1];     // int32 [2,E]
    const float* W    = (const float*)d_in[2];   // fp32 [256,128]
    const float* bias = (const float*)d_in[3];   // fp32 [128]

    const int N = in_sizes[0] / N_FEAT;   // 100000
    const int E = in_sizes[1] / 2;        // 1600000
    const int nb = (N + 255) >> D_BITS;   // 391 coarse buckets

    // workspace layout (~42 MB)
    char* ws = (char*)d_ws;
    size_t off = 0;
    int*          gcur   = (int*)(ws + off);   off += (size_t)NCOPY * 512 * 4;
    int*          cbase  = (int*)(ws + off);   off += 512 * 4;
    int*          rowptr = (int*)(ws + off);   off += (size_t)(N + 4) * 4;
    int*          rend   = (int*)(ws + off);   off += (size_t)(N + 4) * 4;
    float*        dis    = (float*)(ws + off); off += (size_t)N * 4;
    int*          srcs   = (int*)(ws + off);   off += (size_t)E * 4 + 64;
    uint4*        Wf     = (uint4*)(ws + off); off += 4096 * 16;   // 64 KB
    unsigned int* pairs4 = (unsigned int*)(ws + off);
    off += (size_t)NCOPY * NBMAX * CCAP * 4;   // 9.6 MB
    unsigned int* h2     = (unsigned int*)(ws + off);  // (N+1)*64 dwords

    const int half = ((N / 2) + 3) & ~3;   // 50000 (multiple of 4)

    k_pre<<<17, 256, 0, stream>>>(W, (uint4*)Wf, gcur, h2 + (size_t)N * 64);
    k_part<<<(E + TILE - 1) / TILE, 1024, 0, stream>>>(ei, pairs4, gcur, E, nb);
    k_scanb<<<1, 256, 0, stream>>>(gcur, cbase, nb);
    k_fine<<<nb, 1024, 0, stream>>>(pairs4, gcur, cbase, rowptr, rend, dis,
                                    srcs, N);
    k_gemm<<<(N + 127) / 128, 256, 0, stream>>>(x, Wf, dis,
                                                (unsigned short*)h2, N);
    k_aggr<<<(half + 3) / 4, 256, 0, stream>>>(rowptr, rend, srcs,
                                               (const u32x4*)h2, dis, bias,
                                               (float4*)d_out, 0, half, N);
    k_aggr<<<(N - half + 3) / 4, 256, 0, stream>>>(rowptr, rend, srcs,
                                                   (const u32x4*)h2, dis, bias,
                                                   (float4*)d_out, half, N, N);
}